// Round 1
// baseline (154.708 us; speedup 1.0000x reference)
//
#include <hip/hip_runtime.h>
#include <hip/hip_bf16.h>

#define BATCH  4096
#define NUM_GO 30000
#define DIM    128

#define BM      128       // rows per block: 4 waves x 2 row-tiles x 16
#define THREADS 256
#define CPS     2         // 64-GO chunks per block
constexpr int NCHUNKS = (NUM_GO + 63) / 64;          // 469 (last: 3 subtiles)
constexpr int NSEG    = (NCHUNKS + CPS - 1) / CPS;   // 235 (last seg: 1 chunk)
constexpr int NGO_PAD = NCHUNKS * 64;                // 30016
constexpr int NFRAGP  = (NGO_PAD / 16) * 4 * 64;     // 480256 16B fragments
#define CHUNK_BYTES 16384                             // 64 go x 128 dim x 2B
#define NBLK    ((BATCH / BM) * NSEG)                 // 7520 = 8 x 940

typedef __bf16 bf16x8 __attribute__((ext_vector_type(8)));
typedef float  f32x4  __attribute__((ext_vector_type(4)));

__device__ inline short f2bf(float x) {
    __hip_bfloat16 b = __float2bfloat16(x);
    return __builtin_bit_cast(short, b);
}

__device__ __forceinline__ void gload_lds16(const void* g, void* l) {
    __builtin_amdgcn_global_load_lds(
        (const __attribute__((address_space(1))) void*)g,
        (__attribute__((address_space(3))) void*)l, 16, 0, 0);
}

// P: f32 -> bf16 linear
__global__ __launch_bounds__(256) void cvt_bf16(const float* __restrict__ src,
                                                short* __restrict__ dst, int n4) {
    int i = blockIdx.x * blockDim.x + threadIdx.x;
    if (i >= n4) return;
    float4 v = ((const float4*)src)[i];
    short4 o = make_short4(f2bf(v.x), f2bf(v.y), f2bf(v.z), f2bf(v.w));
    ((short4*)dst)[i] = o;
}

// F: f32 -> bf16 packed in MFMA-fragment order, zero-padded to NGO_PAD rows.
__global__ __launch_bounds__(256) void cvt_F_packed(const float* __restrict__ F,
                                                    short* __restrict__ Fp) {
    int t = blockIdx.x * 256 + threadIdx.x;
    if (t >= NFRAGP) return;
    int lcol = t & 15, lrow = (t >> 4) & 3, ks = (t >> 6) & 3, g = t >> 8;
    int row = g * 16 + lcol;
    union { short s[8]; int4 v; } u;
    if (row < NUM_GO) {
        const float* src = F + (size_t)row * DIM + ks * 32 + lrow * 8;
#pragma unroll
        for (int i = 0; i < 8; ++i) u.s[i] = f2bf(src[i]);
    } else {
        u.v = make_int4(0, 0, 0, 0);
    }
    *(int4*)(Fp + (size_t)t * 8) = u.v;
}

// One 64-go chunk. Swapped MFMA mfma(F,P): lane (lcol,lrow), reg i holds
// logits[r = r0 + lcol][go = chunk*64 + t*16 + lrow*4 + i].
// Mask comes from per-lane REGISTERS (direct global loads) -- no LDS trip.
template<int NT>
__device__ __forceinline__ void chunk_compute(
    const short* __restrict__ flds,
    const int4* __restrict__ m0, const int4* __restrict__ m1,
    const bf16x8 a0[4], const bf16x8 a1[4],
    int lane, float s2,
    float& sum0, float& pos0, float& sum1, float& pos1)
{
#pragma unroll
    for (int t = 0; t < NT; ++t) {
        bf16x8 f[4];
#pragma unroll
        for (int ks = 0; ks < 4; ++ks)
            f[ks] = *(const bf16x8*)(flds + (t * 256 + ks * 64 + lane) * 8);
        f32x4 acc0 = {0.f, 0.f, 0.f, 0.f};
        f32x4 acc1 = {0.f, 0.f, 0.f, 0.f};
#pragma unroll
        for (int ks = 0; ks < 4; ++ks) {
            acc0 = __builtin_amdgcn_mfma_f32_16x16x32_bf16(f[ks], a0[ks], acc0, 0, 0, 0);
            acc1 = __builtin_amdgcn_mfma_f32_16x16x32_bf16(f[ks], a1[ks], acc1, 0, 0, 0);
        }
        const int* p0 = reinterpret_cast<const int*>(m0 + t);
        const int* p1 = reinterpret_cast<const int*>(m1 + t);
#pragma unroll
        for (int i = 0; i < 4; ++i) {
            float e0 = __builtin_amdgcn_exp2f(fmaf(acc0[i], s2, -s2));
            float e1 = __builtin_amdgcn_exp2f(fmaf(acc1[i], s2, -s2));
            float w0 = (float)p0[i];        // mask value is exactly {0,1}
            float w1 = (float)p1[i];
            sum0 += e0; pos0 = fmaf(w0, e0, pos0);
            sum1 += e1; pos1 = fmaf(w1, e1, pos1);
        }
    }
}

__global__ __launch_bounds__(THREADS, 4) void infonce_main(
    const short* __restrict__ Pb,   // [BATCH][DIM] bf16
    const short* __restrict__ Fp,   // packed F fragments (padded)
    const int*  __restrict__ mask,  // [BATCH][NUM_GO]
    const float* __restrict__ temp,
    float* __restrict__ rowsum,     // [BATCH] accum (zeroed)
    float* __restrict__ possum)     // [BATCH] accum (zeroed)
{
    __shared__ short flds[CPS * CHUNK_BYTES / 2];          // 32 KB -> 4 blocks/CU

    // bijective XCD-aware decode: blocks of the same GO segment -> same XCD
    const int bid = blockIdx.x;
    const int wid = (bid & 7) * (NBLK / 8) + (bid >> 3);
    const int by  = wid >> 5;       // GO segment 0..234
    const int bx  = wid & 31;       // row-block 0..31

    const int tid  = threadIdx.x;
    const int w    = tid >> 6;
    const int lane = tid & 63;
    const int lcol = lane & 15;
    const int lrow = lane >> 4;

    const int r0 = bx * BM + w * 32 + lcol;
    const int r1 = r0 + 16;

    const int c0 = by * CPS;
    const int nc = (c0 + CPS <= NCHUNKS) ? CPS : (NCHUNKS - c0);   // 2 or 1

    const float s2 = __expf(-temp[0]) * 1.44269504088896f;  // (1/exp(T))*log2e

    bf16x8 a0[4], a1[4];
#pragma unroll
    for (int ks = 0; ks < 4; ++ks) {
        a0[ks] = *(const bf16x8*)(Pb + (size_t)r0 * DIM + ks * 32 + lrow * 8);
        a1[ks] = *(const bf16x8*)(Pb + (size_t)r1 * DIM + ks * 32 + lrow * 8);
    }

    // F staging (L2-resident after first touch per XCD); this is the ONLY
    // traffic drained by the barrier's vmcnt(0).
    {
        const int nbytes = nc * CHUNK_BYTES;
        const char* gbase = (const char*)Fp + (size_t)c0 * CHUNK_BYTES;
        for (int off = w * 1024; off < nbytes; off += 4 * 1024)
            gload_lds16(gbase + off + lane * 16, (char*)flds + off);
    }
    __syncthreads();

    // Mask loads issued AFTER the barrier so they remain in flight across the
    // MFMA/VALU compute and are consumed with counted vmcnt at the fma.
    // Each lane loads exactly the int4s its MFMA output registers need.
    const int* gm0 = mask + (size_t)r0 * NUM_GO + c0 * 64 + lrow * 4;
    const int* gm1 = mask + (size_t)r1 * NUM_GO + c0 * 64 + lrow * 4;

    float sum0 = 0.f, pos0 = 0.f, sum1 = 0.f, pos1 = 0.f;

    if (nc == 2) {
        int4 m0r0[4], m0r1[4], m1r0[4], m1r1[4];
#pragma unroll
        for (int t = 0; t < 4; ++t) {
            m0r0[t] = *(const int4*)(gm0 + t * 16);
            m0r1[t] = *(const int4*)(gm1 + t * 16);
        }
#pragma unroll
        for (int t = 0; t < 4; ++t) {
            m1r0[t] = *(const int4*)(gm0 + 64 + t * 16);
            m1r1[t] = *(const int4*)(gm1 + 64 + t * 16);
        }
        chunk_compute<4>(flds, m0r0, m0r1, a0, a1, lane, s2,
                         sum0, pos0, sum1, pos1);
        chunk_compute<4>(flds + CHUNK_BYTES / 2, m1r0, m1r1, a0, a1, lane, s2,
                         sum0, pos0, sum1, pos1);
    } else {
        // chunk 468 (the only NT=3 one) is alone in segment 234
        int4 m0r0[3], m0r1[3];
#pragma unroll
        for (int t = 0; t < 3; ++t) {
            m0r0[t] = *(const int4*)(gm0 + t * 16);
            m0r1[t] = *(const int4*)(gm1 + t * 16);
        }
        chunk_compute<3>(flds, m0r0, m0r1, a0, a1, lane, s2,
                         sum0, pos0, sum1, pos1);
    }

    // combine the 4 lrow replicas of each row's partials, 1 atomic per row
    sum0 += __shfl_xor(sum0, 16); sum0 += __shfl_xor(sum0, 32);
    pos0 += __shfl_xor(pos0, 16); pos0 += __shfl_xor(pos0, 32);
    sum1 += __shfl_xor(sum1, 16); sum1 += __shfl_xor(sum1, 32);
    pos1 += __shfl_xor(pos1, 16); pos1 += __shfl_xor(pos1, 32);
    if (lane < 16) {
        atomicAdd(&rowsum[r0], sum0);
        atomicAdd(&possum[r0], pos0);
        atomicAdd(&rowsum[r1], sum1);
        atomicAdd(&possum[r1], pos1);
    }
}

__global__ __launch_bounds__(256) void infonce_finalize(
    const float* __restrict__ rowsum, const float* __restrict__ possum,
    float* __restrict__ out)
{
    float acc = 0.f;
    for (int r = threadIdx.x; r < BATCH; r += 256) {
        float p = possum[r], sm = rowsum[r];
        if (p > 0.f) acc += -logf(p / sm + 1e-8f);   // has_pos <=> pos_sum > 0
    }
    __shared__ float red[4];
#pragma unroll
    for (int off = 32; off >= 1; off >>= 1) acc += __shfl_down(acc, off);
    if ((threadIdx.x & 63) == 0) red[threadIdx.x >> 6] = acc;
    __syncthreads();
    if (threadIdx.x == 0)
        out[0] = (red[0] + red[1] + red[2] + red[3]) * (1.0f / BATCH);
}

extern "C" void kernel_launch(void* const* d_in, const int* in_sizes, int n_in,
                              void* d_out, int out_size, void* d_ws, size_t ws_size,
                              hipStream_t stream) {
    const float* P    = (const float*)d_in[0];
    const float* F    = (const float*)d_in[1];
    const int*   mask = (const int*)d_in[2];
    const float* temp = (const float*)d_in[3];
    float* out = (float*)d_out;

    // ws: rowsum[4096] | possum[4096] | P_bf16 (1 MB) | F_packed (~7.7 MB)
    char* ws = (char*)d_ws;
    float* rowsum = (float*)ws;
    float* possum = (float*)(ws + 16384);
    short* Pb     = (short*)(ws + 32768);
    short* Fp     = (short*)(ws + 32768 + (size_t)BATCH * DIM * 2);

    hipMemsetAsync(rowsum, 0, 32768, stream);

    int nP4 = BATCH * DIM / 4;
    cvt_bf16<<<(nP4 + 255) / 256, 256, 0, stream>>>(P, Pb, nP4);
    cvt_F_packed<<<(NFRAGP + 255) / 256, 256, 0, stream>>>(F, Fp);

    infonce_main<<<NBLK, THREADS, 0, stream>>>(Pb, Fp, mask, temp,
                                               rowsum, possum);
    infonce_finalize<<<1, 256, 0, stream>>>(rowsum, possum, out);
}

// Round 2
// 141.507 us; speedup vs baseline: 1.0933x; 1.0933x over previous
//
#include <hip/hip_runtime.h>
#include <hip/hip_bf16.h>

#define BATCH  4096
#define NUM_GO 30000
#define DIM    128

#define BM      256       // rows per block: 8 waves x 2 row-tiles x 16
#define THREADS 512
constexpr int NCHUNKS = (NUM_GO + 63) / 64;          // 469 (last: 3 subtiles)
constexpr int NGO_PAD = NCHUNKS * 64;                // 30016
constexpr int NFRAGP  = (NGO_PAD / 16) * 4 * 64;     // 480256 16B fragments
#define CHUNK_BYTES 16384                             // 64 go x 128 dim x 2B
#define MSTRIDE 68                                    // packed-mask row stride (bytes)
#define NGRP    32                                    // chunk-groups
#define NBLK    (16 * NGRP)                           // 512 = 2 blocks/CU, persistent

typedef __bf16 bf16x8 __attribute__((ext_vector_type(8)));
typedef float  f32x4  __attribute__((ext_vector_type(4)));

__device__ inline short f2bf(float x) {
    __hip_bfloat16 b = __float2bfloat16(x);
    return __builtin_bit_cast(short, b);
}

__device__ __forceinline__ void gload_lds16(const void* g, void* l) {
    __builtin_amdgcn_global_load_lds(
        (const __attribute__((address_space(1))) void*)g,
        (__attribute__((address_space(3))) void*)l, 16, 0, 0);
}

// mask values are exactly {0,1}: pack 4 ints -> 4 bytes of one u32
__device__ __forceinline__ unsigned pack01(int4 m) {
    return (unsigned)(m.x | (m.y << 8) | (m.z << 16) | (m.w << 24));
}

// P: f32 -> bf16 linear
__global__ __launch_bounds__(256) void cvt_bf16(const float* __restrict__ src,
                                                short* __restrict__ dst, int n4) {
    int i = blockIdx.x * blockDim.x + threadIdx.x;
    if (i >= n4) return;
    float4 v = ((const float4*)src)[i];
    short4 o = make_short4(f2bf(v.x), f2bf(v.y), f2bf(v.z), f2bf(v.w));
    ((short4*)dst)[i] = o;
}

// F: f32 -> bf16 packed in MFMA-fragment order, zero-padded to NGO_PAD rows.
__global__ __launch_bounds__(256) void cvt_F_packed(const float* __restrict__ F,
                                                    short* __restrict__ Fp) {
    int t = blockIdx.x * 256 + threadIdx.x;
    if (t >= NFRAGP) return;
    int lcol = t & 15, lrow = (t >> 4) & 3, ks = (t >> 6) & 3, g = t >> 8;
    int row = g * 16 + lcol;
    union { short s[8]; int4 v; } u;
    if (row < NUM_GO) {
        const float* src = F + (size_t)row * DIM + ks * 32 + lrow * 8;
#pragma unroll
        for (int i = 0; i < 8; ++i) u.s[i] = f2bf(src[i]);
    } else {
        u.v = make_int4(0, 0, 0, 0);
    }
    *(int4*)(Fp + (size_t)t * 8) = u.v;
}

// One 64-go chunk (NT 16-wide subtiles); F and packed mask both from LDS.
// Swapped MFMA mfma(F,P): lane (lcol,lrow), reg i holds
// logits[r = r0 + lcol][go = chunk*64 + t*16 + lrow*4 + i].
template<int NT>
__device__ __forceinline__ void chunk_compute(
    const short* __restrict__ flds, const unsigned char* __restrict__ mrow,
    const bf16x8 a0[4], const bf16x8 a1[4],
    int w, int lane, int lcol, int lrow, float s2,
    float& sum0, float& pos0, float& sum1, float& pos1)
{
#pragma unroll
    for (int t = 0; t < NT; ++t) {
        bf16x8 f[4];
#pragma unroll
        for (int ks = 0; ks < 4; ++ks)
            f[ks] = *(const bf16x8*)(flds + (t * 256 + ks * 64 + lane) * 8);
        const unsigned pk0 = *(const unsigned*)(mrow + (w * 32 + lcol) * MSTRIDE
                                                     + t * 16 + lrow * 4);
        const unsigned pk1 = *(const unsigned*)(mrow + (w * 32 + 16 + lcol) * MSTRIDE
                                                     + t * 16 + lrow * 4);
        f32x4 acc0 = {0.f, 0.f, 0.f, 0.f};
        f32x4 acc1 = {0.f, 0.f, 0.f, 0.f};
#pragma unroll
        for (int ks = 0; ks < 4; ++ks) {
            acc0 = __builtin_amdgcn_mfma_f32_16x16x32_bf16(f[ks], a0[ks], acc0, 0, 0, 0);
            acc1 = __builtin_amdgcn_mfma_f32_16x16x32_bf16(f[ks], a1[ks], acc1, 0, 0, 0);
        }
#pragma unroll
        for (int i = 0; i < 4; ++i) {
            float e0 = __builtin_amdgcn_exp2f(fmaf(acc0[i], s2, -s2));
            float e1 = __builtin_amdgcn_exp2f(fmaf(acc1[i], s2, -s2));
            float w0 = (float)((pk0 >> (8 * i)) & 0xFFu);   // v_cvt_f32_ubyte
            float w1 = (float)((pk1 >> (8 * i)) & 0xFFu);
            sum0 += e0; pos0 = fmaf(w0, e0, pos0);
            sum1 += e1; pos1 = fmaf(w1, e1, pos1);
        }
    }
}

__global__ __launch_bounds__(THREADS, 4) void infonce_main(
    const short* __restrict__ Pb,   // [BATCH][DIM] bf16
    const short* __restrict__ Fp,   // packed F fragments (padded)
    const int*  __restrict__ mask,  // [BATCH][NUM_GO]
    const float* __restrict__ temp,
    float* __restrict__ rowsum,     // [BATCH] accum (zeroed)
    float* __restrict__ possum)     // [BATCH] accum (zeroed)
{
    __shared__ short flds[2][CHUNK_BYTES / 2];             // 32 KB (double buffer)
    __shared__ unsigned char mpk[2][256 * MSTRIDE];        // 2 x 17 KB
    // total ~66 KB -> 2 blocks/CU, grid 512 = fully resident (persistent)

    // decode: XCD x gets 4 whole chunk-groups (16 bx-blocks each) -> F L2 reuse
    const int bid = blockIdx.x;
    const int x   = bid & 7;
    const int rr  = bid >> 3;           // 0..63
    const int g   = x * 4 + (rr >> 4);  // chunk-group 0..31
    const int bx  = rr & 15;            // row-block 0..15

    // chunks [k0, k0+nk): groups 0..20 get 15 chunks, 21..31 get 14 (469 total)
    const int k0 = g * 14 + (g < 21 ? g : 21);
    const int nk = 14 + (g < 21 ? 1 : 0);

    const int tid  = threadIdx.x;
    const int w    = tid >> 6;
    const int lane = tid & 63;
    const int lcol = lane & 15;
    const int lrow = lane >> 4;

    const int r0 = bx * BM + w * 32 + lcol;
    const int r1 = r0 + 16;

    const float s2 = __expf(-temp[0]) * 1.44269504088896f;  // (1/exp(T))*log2e

    bf16x8 a0[4], a1[4];
#pragma unroll
    for (int ks = 0; ks < 4; ++ks) {
        a0[ks] = *(const bf16x8*)(Pb + (size_t)r0 * DIM + ks * 32 + lrow * 8);
        a1[ks] = *(const bf16x8*)(Pb + (size_t)r1 * DIM + ks * 32 + lrow * 8);
    }

    // cooperative mask staging geometry: thread covers rows srow+32j (j=0..7),
    // 16B of one row per load -> per wave-instr: 4 rows x 256B contiguous
    const int srow = w * 4 + lrow;          // 0..31
    const int i16  = lcol;                  // int4-slot within chunk row
    const size_t growbase = (size_t)(bx * BM + srow) * NUM_GO;

    int4 mv[8];

    // ---- prologue: stage chunk k0 into buffer 0 ----
    {
        int col = k0 * 64 + i16 * 4;
        if (col > NUM_GO - 4) col = NUM_GO - 4;          // tail-safe, dup reads ok
        const int* gp = mask + growbase + col;
#pragma unroll
        for (int j = 0; j < 8; ++j)
            mv[j] = *(const int4*)(gp + (size_t)32 * j * NUM_GO);
        const char* gbase = (const char*)Fp + (size_t)k0 * CHUNK_BYTES;
        for (int off = w * 1024; off < CHUNK_BYTES; off += 8 * 1024)
            gload_lds16(gbase + off + lane * 16, (char*)flds[0] + off);
#pragma unroll
        for (int j = 0; j < 8; ++j)
            *(unsigned*)&mpk[0][(srow + 32 * j) * MSTRIDE + i16 * 4] = pack01(mv[j]);
    }
    __syncthreads();

    float sum0 = 0.f, pos0 = 0.f, sum1 = 0.f, pos1 = 0.f;

    // ---- pipelined main loop: issue k+1, compute k, pack k+1, barrier ----
    for (int i = 0; i < nk; ++i) {
        const int cur  = i & 1;
        const int nxt  = cur ^ 1;
        const bool more = (i + 1 < nk);

        if (more) {
            const int kn = k0 + i + 1;
            int col = kn * 64 + i16 * 4;
            if (col > NUM_GO - 4) col = NUM_GO - 4;
            const int* gp = mask + growbase + col;
#pragma unroll
            for (int j = 0; j < 8; ++j)
                mv[j] = *(const int4*)(gp + (size_t)32 * j * NUM_GO);
            const char* gbase = (const char*)Fp + (size_t)kn * CHUNK_BYTES;
            for (int off = w * 1024; off < CHUNK_BYTES; off += 8 * 1024)
                gload_lds16(gbase + off + lane * 16, (char*)flds[nxt] + off);
        }
        // pin: keep the stage issues ABOVE the compute (loads stay in flight
        // under the MFMA/VALU phase; consumed only at the pack below)
        __builtin_amdgcn_sched_barrier(0);

        if (k0 + i == NCHUNKS - 1)
            chunk_compute<3>(flds[cur], mpk[cur], a0, a1, w, lane, lcol, lrow, s2,
                             sum0, pos0, sum1, pos1);
        else
            chunk_compute<4>(flds[cur], mpk[cur], a0, a1, w, lane, lcol, lrow, s2,
                             sum0, pos0, sum1, pos1);

        if (more) {
            // compiler inserts the exact vmcnt for mv here (gloads still ok)
#pragma unroll
            for (int j = 0; j < 8; ++j)
                *(unsigned*)&mpk[nxt][(srow + 32 * j) * MSTRIDE + i16 * 4] = pack01(mv[j]);
            __syncthreads();   // drains the 2 gload_lds (long since issued) + ds_writes
        }
    }

    // combine the 4 lrow replicas of each row's partials, 1 atomic per row per block
    sum0 += __shfl_xor(sum0, 16); sum0 += __shfl_xor(sum0, 32);
    pos0 += __shfl_xor(pos0, 16); pos0 += __shfl_xor(pos0, 32);
    sum1 += __shfl_xor(sum1, 16); sum1 += __shfl_xor(sum1, 32);
    pos1 += __shfl_xor(pos1, 16); pos1 += __shfl_xor(pos1, 32);
    if (lane < 16) {
        atomicAdd(&rowsum[r0], sum0);
        atomicAdd(&possum[r0], pos0);
        atomicAdd(&rowsum[r1], sum1);
        atomicAdd(&possum[r1], pos1);
    }
}

__global__ __launch_bounds__(256) void infonce_finalize(
    const float* __restrict__ rowsum, const float* __restrict__ possum,
    float* __restrict__ out)
{
    float acc = 0.f;
    for (int r = threadIdx.x; r < BATCH; r += 256) {
        float p = possum[r], sm = rowsum[r];
        if (p > 0.f) acc += -logf(p / sm + 1e-8f);   // has_pos <=> pos_sum > 0
    }
    __shared__ float red[4];
#pragma unroll
    for (int off = 32; off >= 1; off >>= 1) acc += __shfl_down(acc, off);
    if ((threadIdx.x & 63) == 0) red[threadIdx.x >> 6] = acc;
    __syncthreads();
    if (threadIdx.x == 0)
        out[0] = (red[0] + red[1] + red[2] + red[3]) * (1.0f / BATCH);
}

extern "C" void kernel_launch(void* const* d_in, const int* in_sizes, int n_in,
                              void* d_out, int out_size, void* d_ws, size_t ws_size,
                              hipStream_t stream) {
    const float* P    = (const float*)d_in[0];
    const float* F    = (const float*)d_in[1];
    const int*   mask = (const int*)d_in[2];
    const float* temp = (const float*)d_in[3];
    float* out = (float*)d_out;

    // ws: rowsum[4096] | possum[4096] | P_bf16 (1 MB) | F_packed (~7.7 MB)
    char* ws = (char*)d_ws;
    float* rowsum = (float*)ws;
    float* possum = (float*)(ws + 16384);
    short* Pb     = (short*)(ws + 32768);
    short* Fp     = (short*)(ws + 32768 + (size_t)BATCH * DIM * 2);

    hipMemsetAsync(rowsum, 0, 32768, stream);

    int nP4 = BATCH * DIM / 4;
    cvt_bf16<<<(nP4 + 255) / 256, 256, 0, stream>>>(P, Pb, nP4);
    cvt_F_packed<<<(NFRAGP + 255) / 256, 256, 0, stream>>>(F, Fp);

    infonce_main<<<NBLK, THREADS, 0, stream>>>(Pb, Fp, mask, temp,
                                               rowsum, possum);
    infonce_finalize<<<1, 256, 0, stream>>>(rowsum, possum, out);
}